// Round 1
// 801.339 us; speedup vs baseline: 1.0157x; 1.0157x over previous
//
#include <hip/hip_runtime.h>

// 2-layer GCN, gather formulation via device-built CSR:
//   dinv = rsqrt(1 + indeg)
//   g1 = dinv * (x @ W1)        -- now bf16-split MFMA (hi*hi + lo*hi + hi*lo)
//   row(v) = relu(b1 + dinv[v]*(g1[v] + sum_{in} g1[src]))
//   g2[v] = dinv[v] * (row(v) @ W2)           (fused into gather1 kernel)
//   out[v] = b2 + dinv[v]*(g2[v] + sum_{in} g2[src])

constexpr int C1 = 64;
constexpr int C2 = 32;
constexpr int K1 = 768;
constexpr int SCAN_BS = 256;
constexpr int SCAN_ELEMS = 2048;   // 8 per thread

typedef __attribute__((ext_vector_type(8))) short short8;
typedef __attribute__((ext_vector_type(4))) float floatx4;

// ---------- edge dtype detection (device-side, graph-capture safe) ----------
__global__ void detect_k(const int* __restrict__ ei32, int* flag, int n_words) {
    __shared__ int any_nz;
    if (threadIdx.x == 0) any_nz = 0;
    __syncthreads();
    int w = 2 * threadIdx.x + 1;     // odd words = high halves if int64
    if (w < n_words && ei32[w] != 0) atomicOr(&any_nz, 1);
    __syncthreads();
    if (threadIdx.x == 0) *flag = (any_nz == 0) ? 1 : 0;
}

__device__ __forceinline__ int load_idx(const void* ei, size_t pos, int m64) {
    if (m64) return (int)((const long long*)ei)[pos];
    return ((const int*)ei)[pos];
}

// ---------- degree ----------
__global__ void zero_k(int* p, int n) {
    int i = blockIdx.x * 256 + threadIdx.x;
    if (i < n) p[i] = 0;
}

__global__ void cnt_k(const void* __restrict__ ei, const int* __restrict__ flag,
                      int* cnt, int E) {
    int e = blockIdx.x * 256 + threadIdx.x;
    if (e >= E) return;
    int m64 = *flag;
    int d = load_idx(ei, (size_t)E + e, m64);
    atomicAdd(&cnt[d], 1);
}

__global__ void dinv_k(const int* __restrict__ cnt, float* dinv, int n) {
    int i = blockIdx.x * 256 + threadIdx.x;
    if (i < n) dinv[i] = rsqrtf(1.0f + (float)cnt[i]);   // +1 self-loop
}

// ---------- block scan (exclusive) over cnt -> offsets, cursor ----------
__global__ void scan1_k(const int* __restrict__ cnt, int* partials, int n) {
    __shared__ int s[SCAN_BS];
    int base = blockIdx.x * SCAN_ELEMS;
    int t = threadIdx.x;
    int sum = 0;
    #pragma unroll
    for (int i = 0; i < 8; ++i) {
        int idx = base + t * 8 + i;
        if (idx < n) sum += cnt[idx];
    }
    s[t] = sum;
    __syncthreads();
    for (int off = 128; off > 0; off >>= 1) {
        if (t < off) s[t] += s[t + off];
        __syncthreads();
    }
    if (t == 0) partials[blockIdx.x] = s[0];
}

__global__ void scan2_k(int* partials, int* total_out, int nb) {
    __shared__ int s[256];
    int t = threadIdx.x;
    int v = (t < nb) ? partials[t] : 0;
    s[t] = v;
    __syncthreads();
    for (int off = 1; off < 256; off <<= 1) {
        int add = (t >= off) ? s[t - off] : 0;
        __syncthreads();
        s[t] += add;
        __syncthreads();
    }
    if (t < nb) partials[t] = s[t] - v;     // exclusive block offsets
    if (t == 0) *total_out = s[255];        // offsets[n]
}

__global__ void scan3_k(const int* __restrict__ cnt, const int* __restrict__ partials,
                        int* offsets, int* cursor, int n) {
    __shared__ int s[SCAN_BS];
    int base = blockIdx.x * SCAN_ELEMS;
    int t = threadIdx.x;
    int local[8];
    int sum = 0;
    #pragma unroll
    for (int i = 0; i < 8; ++i) {
        int idx = base + t * 8 + i;
        int v = (idx < n) ? cnt[idx] : 0;
        local[i] = sum;
        sum += v;
    }
    int mine = sum;
    s[t] = sum;
    __syncthreads();
    for (int off = 1; off < 256; off <<= 1) {
        int add = (t >= off) ? s[t - off] : 0;
        __syncthreads();
        s[t] += add;
        __syncthreads();
    }
    int texcl = s[t] - mine;
    int boff = partials[blockIdx.x];
    #pragma unroll
    for (int i = 0; i < 8; ++i) {
        int idx = base + t * 8 + i;
        if (idx < n) {
            int o = boff + texcl + local[i];
            offsets[idx] = o;
            cursor[idx] = o;
        }
    }
}

// ---------- CSR fill ----------
__global__ void fill_k(const void* __restrict__ ei, const int* __restrict__ flag,
                       int* cursor, int* adj, int E) {
    int e = blockIdx.x * 256 + threadIdx.x;
    if (e >= E) return;
    int m64 = *flag;
    int s = load_idx(ei, e, m64);
    int d = load_idx(ei, (size_t)E + e, m64);
    int pos = atomicAdd(&cursor[d], 1);
    adj[pos] = s;
}

// ---------- bf16 split helpers (RNE both halves) ----------
__device__ __forceinline__ void bf16_split(float f, unsigned short& hi, unsigned short& lo) {
    unsigned int u = __float_as_uint(f);
    unsigned int r1 = (u + 0x7FFFu + ((u >> 16) & 1u)) & 0xFFFF0000u;
    hi = (unsigned short)(r1 >> 16);
    float rem = f - __uint_as_float(r1);
    unsigned int u2 = __float_as_uint(rem);
    lo = (unsigned short)((u2 + 0x7FFFu + ((u2 >> 16) & 1u)) >> 16);
}

// ---------- pack W1 into per-lane MFMA B-fragments (hi/lo planes) ----------
// Fragment (s,t,p): k-step s (32 k), col-tile t (16 cols), plane p (0=hi,1=lo).
// Lane l holds col = 16t + (l&15), k = 32s + 8*(l>>4) + j, j=0..7.
// Layout: Bp[ fi*512 + l*8 + j ] ushorts, fi = (s*4 + t)*2 + p.  Total 24*4*2*512*2B = 192 KB.
__global__ void packW1_k(const float* __restrict__ W1, unsigned short* __restrict__ Bp) {
    int gid = blockIdx.x * 256 + threadIdx.x;
    if (gid >= 24 * 4 * 2 * 64) return;
    int l    = gid & 63;
    int frag = gid >> 6;
    int p = frag & 1;
    int t = (frag >> 1) & 3;
    int s = frag >> 3;
    int c = t * 16 + (l & 15);
    int kbase = s * 32 + (l >> 4) * 8;
    short8 v;
    #pragma unroll
    for (int j = 0; j < 8; ++j) {
        unsigned short hi, lo;
        bf16_split(W1[(size_t)(kbase + j) * C1 + c], hi, lo);
        v[j] = (short)(p ? lo : hi);
    }
    *(short8*)(Bp + (size_t)gid * 8) = v;
}

// ---------- GEMM1 (MFMA, bf16-split): g1[n,64] = dinv * (x[n,768] @ W1) ----------
// 128 rows/block, 4 waves; wave w owns rows [w*32, w*32+32) as two 16-row A-frags.
// A staged fp32 in LDS via global_load_lds (16B), XOR-swizzled 16B blocks so the
// per-lane ds_read_b128 fragment reads are conflict-free; split to bf16 in regs.
// 3 MFMA per (A-frag, col-tile): hi*hi + lo*hi + hi*lo  (~2^-17 rel err).
__global__ __launch_bounds__(256) void gemm1_k(const float* __restrict__ x,
                                               const unsigned short* __restrict__ Bp,
                                               const float* __restrict__ dinv,
                                               float* __restrict__ g1, int n) {
    constexpr int MT = 128;
    __shared__ float As[MT * 32];           // 16 KB, swizzled 16B blocks
    const int tid = threadIdx.x;
    const int w = tid >> 6;                 // wave 0..3
    const int l = tid & 63;                 // lane
    const int block_row = blockIdx.x * MT;

    floatx4 zero = {0.f, 0.f, 0.f, 0.f};
    floatx4 acc[2][4];
    #pragma unroll
    for (int r = 0; r < 2; ++r)
        #pragma unroll
        for (int t = 0; t < 4; ++t) acc[r][t] = zero;

    // staging geometry: glds inst g covers rows [g*8, g*8+8); lane i writes 16B at
    // LDS float-offset g*256 + i*4  ==  (g*8 + (i>>3))*32 + (i&7)*4.
    // logical kb stored at phys (i&7):  kb = (i&7) ^ (i>>3)  (XOR by row&7).
    const int srow = l >> 3;                // row within 8-row group
    const int skb  = (l & 7) ^ srow;        // logical 16B k-block for this lane

    for (int s = 0; s < 24; ++s) {
        const int k0 = s * 32;
        // ---- stage A tile (16 KB): wave w issues insts g = w*4 .. w*4+3 ----
        #pragma unroll
        for (int gi = 0; gi < 4; ++gi) {
            int g = w * 4 + gi;
            int row = block_row + g * 8 + srow;
            if (row > n - 1) row = n - 1;            // clamp tail (rows unused on store)
            const float* src = x + (size_t)row * K1 + k0 + skb * 4;
            float* ldst = &As[g * 256];              // wave-uniform base
            __builtin_amdgcn_global_load_lds(
                (const __attribute__((address_space(1))) void*)src,
                (__attribute__((address_space(3))) void*)ldst, 16, 0, 0);
        }
        // ---- load B fragments (L2-resident, coalesced 1KB/inst) ----
        short8 bh[4], bl[4];
        #pragma unroll
        for (int t = 0; t < 4; ++t) {
            size_t fb = ((size_t)(s * 4 + t) * 2) * 512;
            bh[t] = *(const short8*)(Bp + fb + l * 8);
            bl[t] = *(const short8*)(Bp + fb + 512 + l * 8);
        }
        __syncthreads();                     // drains vmcnt: A in LDS, B in regs
        // ---- compute ----
        #pragma unroll
        for (int r = 0; r < 2; ++r) {
            int row_local = w * 32 + r * 16 + (l & 15);
            int swz = l & 7;                           // == row_local & 7
            int kb0 = ((l >> 4) * 2) ^ swz;            // phys block of logical 2*(l>>4)
            floatx4 f0 = *(const floatx4*)&As[row_local * 32 + kb0 * 4];
            floatx4 f1 = *(const floatx4*)&As[row_local * 32 + (kb0 ^ 1) * 4];
            short8 ah, al;
            float fv[8] = {f0[0], f0[1], f0[2], f0[3], f1[0], f1[1], f1[2], f1[3]};
            #pragma unroll
            for (int j = 0; j < 8; ++j) {
                unsigned short h16, l16;
                bf16_split(fv[j], h16, l16);
                ah[j] = (short)h16;
                al[j] = (short)l16;
            }
            #pragma unroll
            for (int t = 0; t < 4; ++t) {
                acc[r][t] = __builtin_amdgcn_mfma_f32_16x16x32_bf16(ah, bh[t], acc[r][t], 0, 0, 0);
                acc[r][t] = __builtin_amdgcn_mfma_f32_16x16x32_bf16(al, bh[t], acc[r][t], 0, 0, 0);
                acc[r][t] = __builtin_amdgcn_mfma_f32_16x16x32_bf16(ah, bl[t], acc[r][t], 0, 0, 0);
            }
        }
        __syncthreads();                     // all reads done before next stage
    }

    // ---- epilogue: C/D map col=lane&15, row=(lane>>4)*4+i (m89-verified) ----
    #pragma unroll
    for (int r = 0; r < 2; ++r) {
        #pragma unroll
        for (int i = 0; i < 4; ++i) {
            int row = block_row + w * 32 + r * 16 + (l >> 4) * 4 + i;
            if (row < n) {
                float dv = dinv[row];
                #pragma unroll
                for (int t = 0; t < 4; ++t) {
                    g1[(size_t)row * C1 + t * 16 + (l & 15)] = acc[r][t][i] * dv;
                }
            }
        }
    }
}

// ---------- layer-1 gather + fused GEMM2 ----------
// one wave per node (lane = channel). After gathering the 64-wide row,
// the wave computes h2 = relu(row)@W2 via LDS and writes g2 = dinv*h2.
__global__ __launch_bounds__(256) void gather1_k(const int* __restrict__ offsets,
                                                 const int* __restrict__ adj,
                                                 const float* __restrict__ dinv,
                                                 const float* __restrict__ g1,
                                                 const float* __restrict__ b1,
                                                 const float* __restrict__ W2,
                                                 float* __restrict__ g2, int n) {
    __shared__ float sW[C1 * C2];    // 8 KB
    __shared__ float srow[4][C1];
    const int tid = threadIdx.x;
    for (int i = tid; i < C1 * C2; i += 256) sW[i] = W2[i];

    const int wid = tid >> 6;
    const int c = tid & 63;
    const int v = blockIdx.x * 4 + wid;

    float r = 0.f;
    float dv = 0.f;
    if (v < n) {
        dv = dinv[v];
        int start = offsets[v], end = offsets[v + 1];
        float acc = g1[(size_t)v * C1 + c];          // self-loop term
        int j = start;
        for (; j + 4 <= end; j += 4) {
            int s0 = adj[j], s1 = adj[j + 1], s2 = adj[j + 2], s3 = adj[j + 3];
            float a0 = g1[(size_t)s0 * C1 + c];
            float a1 = g1[(size_t)s1 * C1 + c];
            float a2 = g1[(size_t)s2 * C1 + c];
            float a3 = g1[(size_t)s3 * C1 + c];
            acc += (a0 + a1) + (a2 + a3);
        }
        for (; j < end; ++j) acc += g1[(size_t)adj[j] * C1 + c];
        r = fmaxf(b1[c] + dv * acc, 0.f);            // fused bias + relu
    }
    srow[wid][c] = r;
    __syncthreads();                                  // covers sW + srow

    if (v < n && c < C2) {
        float acc = 0.f;
        #pragma unroll
        for (int k = 0; k < C1; ++k) acc += srow[wid][k] * sW[k * C2 + c];
        g2[(size_t)v * C2 + c] = dv * acc;
    }
}

// ---------- layer-2 gather (2 nodes per wave, 32 lanes each) ----------
__global__ __launch_bounds__(256) void gather2_k(const int* __restrict__ offsets,
                                                 const int* __restrict__ adj,
                                                 const float* __restrict__ dinv,
                                                 const float* __restrict__ g2,
                                                 const float* __restrict__ b2,
                                                 float* __restrict__ out, int n) {
    int v = blockIdx.x * 8 + (threadIdx.x >> 5);
    int c = threadIdx.x & 31;
    if (v >= n) return;
    int start = offsets[v], end = offsets[v + 1];
    float acc = g2[(size_t)v * C2 + c];              // self-loop term
    int j = start;
    for (; j + 4 <= end; j += 4) {
        int s0 = adj[j], s1 = adj[j + 1], s2 = adj[j + 2], s3 = adj[j + 3];
        float a0 = g2[(size_t)s0 * C2 + c];
        float a1 = g2[(size_t)s1 * C2 + c];
        float a2 = g2[(size_t)s2 * C2 + c];
        float a3 = g2[(size_t)s3 * C2 + c];
        acc += (a0 + a1) + (a2 + a3);
    }
    for (; j < end; ++j) acc += g2[(size_t)adj[j] * C2 + c];
    out[(size_t)v * C2 + c] = b2[c] + dinv[v] * acc;
}

extern "C" void kernel_launch(void* const* d_in, const int* in_sizes, int n_in,
                              void* d_out, int out_size, void* d_ws, size_t ws_size,
                              hipStream_t stream) {
    const float* x  = (const float*)d_in[0];
    const void*  ei = d_in[1];
    const float* W1 = (const float*)d_in[2];
    const float* b1 = (const float*)d_in[3];
    const float* W2 = (const float*)d_in[4];
    const float* b2 = (const float*)d_in[5];
    float* out = (float*)d_out;

    const int n = in_sizes[0] / K1;     // 100000
    const int E = in_sizes[1] / 2;      // 1600000

    // workspace layout (all 4-byte types)
    float* ws      = (float*)d_ws;
    int*   flag    = (int*)ws;                      // 16-float header
    float* dinv    = ws + 16;                       // n
    float* g1      = dinv + n;                      // n*64
    float* g2      = g1 + (size_t)n * C1;           // n*32
    int*   cnt     = (int*)(g2 + (size_t)n * C2);   // n
    int*   offsets = cnt + n;                       // n+1
    int*   cursor  = offsets + n + 1;               // n
    int*   partials= cursor + n;                    // 256 (padded)
    int*   adj     = partials + 256;                // E
    uintptr_t bp_a = ((uintptr_t)(adj + E) + 15) & ~(uintptr_t)15;
    unsigned short* Bp = (unsigned short*)bp_a;     // 192 KB packed W1 fragments

    const int nb_scan = (n + SCAN_ELEMS - 1) / SCAN_ELEMS;   // 49

    detect_k<<<1, 256, 0, stream>>>((const int*)ei, flag, in_sizes[1]);
    zero_k<<<(n + 255) / 256, 256, 0, stream>>>(cnt, n);
    cnt_k<<<(E + 255) / 256, 256, 0, stream>>>(ei, flag, cnt, E);
    dinv_k<<<(n + 255) / 256, 256, 0, stream>>>(cnt, dinv, n);

    packW1_k<<<48, 256, 0, stream>>>(W1, Bp);
    gemm1_k<<<(n + 127) / 128, 256, 0, stream>>>(x, Bp, dinv, g1, n);

    scan1_k<<<nb_scan, SCAN_BS, 0, stream>>>(cnt, partials, n);
    scan2_k<<<1, 256, 0, stream>>>(partials, offsets + n, nb_scan);
    scan3_k<<<nb_scan, SCAN_BS, 0, stream>>>(cnt, partials, offsets, cursor, n);
    fill_k<<<(E + 255) / 256, 256, 0, stream>>>(ei, flag, cursor, adj, E);

    gather1_k<<<(n + 3) / 4, 256, 0, stream>>>(offsets, adj, dinv, g1, b1, W2, g2, n);
    gather2_k<<<(n + 7) / 8, 256, 0, stream>>>(offsets, adj, dinv, g2, b2, out, n);
}